// Round 1
// baseline (7300.496 us; speedup 1.0000x reference)
//
#include <hip/hip_runtime.h>
#include <stdint.h>

#define LSEQ  512
#define VOCAB 32000
#define GCOLS 3072               // 3*H2 per direction
#define WHH_STRIDE 1032          // 1024 + 8 halfs pad (16B)

typedef __attribute__((ext_vector_type(8))) short short8;
typedef __attribute__((ext_vector_type(4))) float f32x4;
typedef unsigned short u16;
typedef unsigned int   u32;
typedef unsigned long long u64;

__device__ __forceinline__ float b2f(u16 u) {
  union { u32 i; float f; } x; x.i = ((u32)u) << 16; return x.f;
}
__device__ __forceinline__ u16 f2b(float f) {
  union { float f; u32 i; } x; x.f = f;
  u32 r = (x.i + 0x7fffu + ((x.i >> 16) & 1u)) >> 16;
  return (u16)r;
}
__device__ __forceinline__ void load_lds16(const void* g, void* l) {
  __builtin_amdgcn_global_load_lds(
      (const __attribute__((address_space(1))) void*)g,
      (__attribute__((address_space(3))) void*)l, 16, 0, 0);
}
__device__ __forceinline__ float sigmoidf_(float x) {
  return __builtin_amdgcn_rcpf(1.f + __expf(-x));
}
__device__ __forceinline__ float tanhf_(float x) {
  x = fminf(fmaxf(x, -30.f), 30.f);
  float e = __expf(2.f * x);
  return (e - 1.f) * __builtin_amdgcn_rcpf(e + 1.f);
}

// ---------------------------------------------------------------------------
// Phase 0: f32 -> bf16 (RNE) bulk conversion into workspace.
// ---------------------------------------------------------------------------
__global__ __launch_bounds__(256) void k_cvt(const float* __restrict__ s,
                                             u16* __restrict__ d, int n) {
  int i = (blockIdx.x * 256 + threadIdx.x) * 4;
  if (i >= n) return;
  float4 v = *(const float4*)(s + i);
  u32 lo = (u32)f2b(v.x) | ((u32)f2b(v.y) << 16);
  u32 hi = (u32)f2b(v.z) | ((u32)f2b(v.w) << 16);
  uint2 pk; pk.x = lo; pk.y = hi;
  *(uint2*)(d + i) = pk;
}

// ---------------------------------------------------------------------------
// Phase 1: E'[v, g] = sum_k emb[v,k] * Wih[g,k] + bih[g]  (both dirs).
// Unchanged (verified correct).
// ---------------------------------------------------------------------------
__global__ __launch_bounds__(256) void k_gx(
    const u16* __restrict__ emb,
    const u16* __restrict__ Wf, const float* __restrict__ bf,
    const u16* __restrict__ Wr, const float* __restrict__ br,
    u16* __restrict__ Ef, u16* __restrict__ Er)
{
  __shared__ u16 lA[128 * 64];
  __shared__ u16 lB[128 * 64];
  const int bid = blockIdx.x;
  const int mt = bid % 48;
  const int nt = bid / 48;
  const u16*   W    = (mt < 24) ? Wf : Wr;
  const float* bias = (mt < 24) ? bf : br;
  u16*         Eo   = (mt < 24) ? Ef : Er;
  const int m0 = (mt < 24 ? mt : mt - 24) * 128;
  const int n0 = nt * 128;
  const int tid = threadIdx.x;
  const int lane = tid & 63, wv = tid >> 6;
  const int wA = wv & 1, wB = wv >> 1;
  const int lm = lane & 15, lk = lane >> 4;

  f32x4 acc[4][4];
#pragma unroll
  for (int i = 0; i < 4; ++i)
#pragma unroll
    for (int j = 0; j < 4; ++j) acc[i][j] = (f32x4){0.f, 0.f, 0.f, 0.f};

  for (int k0 = 0; k0 < 1024; k0 += 64) {
#pragma unroll
    for (int it = 0; it < 4; ++it) {
      int slot = it * 256 + tid;
      int row = slot >> 3, seg = slot & 7;
      load_lds16(W + (size_t)(m0 + row) * 1024 + k0 + seg * 8,
                 lA + (size_t)(it * 256 + wv * 64) * 8);
      load_lds16(emb + (size_t)(n0 + row) * 1024 + k0 + seg * 8,
                 lB + (size_t)(it * 256 + wv * 64) * 8);
    }
    __syncthreads();
#pragma unroll
    for (int kc = 0; kc < 2; ++kc) {
      short8 af[4], bfr[4];
#pragma unroll
      for (int i = 0; i < 4; ++i)
        af[i] = *(const short8*)&lA[(64 * wA + 16 * i + lm) * 64 + kc * 32 + lk * 8];
#pragma unroll
      for (int j = 0; j < 4; ++j)
        bfr[j] = *(const short8*)&lB[(64 * wB + 16 * j + lm) * 64 + kc * 32 + lk * 8];
#pragma unroll
      for (int i = 0; i < 4; ++i)
#pragma unroll
        for (int j = 0; j < 4; ++j)
          acc[i][j] = __builtin_amdgcn_mfma_f32_16x16x32_bf16(af[i], bfr[j], acc[i][j], 0, 0, 0);
    }
    __syncthreads();
  }

#pragma unroll
  for (int i = 0; i < 4; ++i) {
    int gcol0 = m0 + 64 * wA + 16 * i + lk * 4;
    const float* bp = bias + gcol0;
    float b0 = bp[0], b1 = bp[1], b2_ = bp[2], b3 = bp[3];
#pragma unroll
    for (int j = 0; j < 4; ++j) {
      int vrow = n0 + 64 * wB + 16 * j + lm;
      f32x4 v = acc[i][j];
      u32 lo = (u32)f2b(v.x + b0) | ((u32)f2b(v.y + b1) << 16);
      u32 hi = (u32)f2b(v.z + b2_) | ((u32)f2b(v.w + b3) << 16);
      uint2 pk; pk.x = lo; pk.y = hi;
      *(uint2*)(Eo + (size_t)vrow * GCOLS + gcol0) = pk;
    }
  }
}

// ---------------------------------------------------------------------------
// Phase 2: persistent GRU recurrence. CACHED-EXCHANGE design (new):
//  - h stores: plain u16 stores -> dirty lines in the writer XCD's L2.
//  - release:  agent fence before barrier-arrive => buffer_wbl2 publishes the
//    ~2KB/WG of dirty h lines to IF. (__syncthreads' vmcnt(0) drain guarantees
//    the stores are in L2 first.)
//  - acquire:  agent fence after the spin => buffer_inv invalidates L1+L2, so
//    next step's h loads are IF-fresh.
//  - h loads:  PLAIN uint4 (global_load_dwordx4) loads. Fully coalesced, and
//    L2-cacheable: all 32 WGs on an XCD belong to the same (d,g) group (with
//    round-robin bid->XCD, bid%8 fixes bid&3), so they share one 128KB h half
//    per step. IF read traffic drops ~32x (32MB -> ~1MB/step) and the ~4.2M
//    uncoalesced 8B bypass-atomic requests/step disappear.
//  - barrier:  relaxed agent add + relaxed agent spin load (unchanged; the
//    spin load bypasses L2 so it is always fresh).
//  - gx double-buffered in LDS; E(t+1) prefetched into regs at top of step.
// ---------------------------------------------------------------------------
__global__ __launch_bounds__(256, 1) void k_rnn(
    const int* __restrict__ seq,
    const u16* __restrict__ Ef, const u16* __restrict__ Er,
    const u16* __restrict__ Whf, const float* __restrict__ bhf,
    const u16* __restrict__ Whr, const float* __restrict__ bhr,
    u16* __restrict__ hbuf, int* __restrict__ bars,
    float* __restrict__ out)
{
  extern __shared__ u16 lds[];
  u16* whh = lds;                           // [48][WHH_STRIDE]
  u16* gx  = lds + 48 * WHH_STRIDE;         // [2][64][64] double buffer
  const int bid = blockIdx.x;
  const int d = bid & 1, g = (bid >> 1) & 1, cw = bid >> 2;
  const int c0 = cw * 16;
  const int barid = (bid & 3) * 32;         // 128B-separated counters
  const u16*   Wh = d ? Whr : Whf;
  const float* bh = d ? bhr : bhf;
  const u16*   E  = d ? Er  : Ef;
  const int tid = threadIdx.x;
  const int lane = tid & 63, wv = tid >> 6;
  const int lm = lane & 15, lk = lane >> 4;

  // --- stage Whh slice: LDS row gate*16+jc <- Wh[gate*1024 + c0 + jc][:]
  for (int it = 0; it < 24; ++it) {
    int idx = it * 256 + tid;
    int row = idx >> 7, q = idx & 127;
    int gate = row >> 4, jc = row & 15;
    uint4 v = *(const uint4*)(Wh + (size_t)((gate << 10) + c0 + jc) * 1024 + q * 8);
    *(uint4*)(whh + (size_t)row * WHH_STRIDE + q * 8) = v;
  }
  const float bhrv = bh[c0 + lm];
  const float bhzv = bh[1024 + c0 + lm];
  const float bhnv = bh[2048 + c0 + lm];

  float hprev[4] = {0.f, 0.f, 0.f, 0.f};
  const int rowA = g * 64 + wv * 16 + lm;

  const int sr_r = tid / 3;                 // gx staging: threads 0..191
  const int sr_s = tid - sr_r * 3;
  const int sr_b = g * 64 + sr_r;
  const int sr_seqrow = d ? (127 - sr_b) : sr_b;
  const bool stager = (tid < 192);

  // prime gx(0) into buffer 0
  if (stager) {
    int tok = seq[sr_seqrow * LSEQ + 0];
    const u16* src = E + (size_t)tok * GCOLS + sr_s * 1024 + c0;
    uint4 v0 = *(const uint4*)src;
    uint4 v1 = *(const uint4*)(src + 8);
    *(uint4*)(gx + sr_r * 64 + sr_s * 16) = v0;
    *(uint4*)(gx + sr_r * 64 + sr_s * 16 + 8) = v1;
  }
  __syncthreads();   // whh + gx(0) ready

  const u16* whp0 = whh + (size_t)lm * WHH_STRIDE + lk * 8;
  const u16* whp1 = whh + (size_t)(16 + lm) * WHH_STRIDE + lk * 8;
  const u16* whp2 = whh + (size_t)(32 + lm) * WHH_STRIDE + lk * 8;

  for (int t = 0; t < LSEQ; ++t) {
    // ---- prefetch E(t+1) into regs (latency overlaps h-loads + MFMA)
    uint4 pf0, pf1;
    const bool havepf = stager && (t + 1 < LSEQ);
    if (havepf) {
      int tok = seq[sr_seqrow * LSEQ + t + 1];
      const u16* src = E + (size_t)tok * GCOLS + sr_s * 1024 + c0;
      pf0 = *(const uint4*)src;
      pf1 = *(const uint4*)(src + 8);
    }

    // ---- h(t) loads: plain cached coalesced loads (L2-shared within XCD;
    //      freshness guaranteed by the acquire fence at the last barrier)
    const u16* hb = hbuf + ((size_t)((t & 1) * 256 + d * 128 + rowA)) * 1024 + lk * 8;
    uint4 hv[32];
#pragma unroll
    for (int kc = 0; kc < 32; ++kc)
      hv[kc] = *(const uint4*)(hb + kc * 32);

    // ---- gh = h @ Whh_slice^T
    f32x4 a0 = (f32x4){0.f,0.f,0.f,0.f};
    f32x4 a1 = (f32x4){0.f,0.f,0.f,0.f};
    f32x4 a2 = (f32x4){0.f,0.f,0.f,0.f};
#pragma unroll
    for (int kc = 0; kc < 32; ++kc) {
      union { uint4 v; short8 s; } u;
      u.v = hv[kc];
      short8 av  = u.s;
      short8 b0v = *(const short8*)(whp0 + kc * 32);
      short8 b1v = *(const short8*)(whp1 + kc * 32);
      short8 b2v = *(const short8*)(whp2 + kc * 32);
      a0 = __builtin_amdgcn_mfma_f32_16x16x32_bf16(av, b0v, a0, 0, 0, 0);
      a1 = __builtin_amdgcn_mfma_f32_16x16x32_bf16(av, b1v, a1, 0, 0, 0);
      a2 = __builtin_amdgcn_mfma_f32_16x16x32_bf16(av, b2v, a2, 0, 0, 0);
    }

    // ---- gates + state update (C layout: col=c0+lm, row=lk*4+i)
    const u16* gxr_ = gx + (t & 1) * 4096;
    u16* hnext = hbuf + ((size_t)(((t + 1) & 1) * 256 + d * 128 + g * 64)) * 1024;
#pragma unroll
    for (int i = 0; i < 4; ++i) {
      int grow = wv * 16 + lk * 4 + i;
      float gxr = b2f(gxr_[grow * 64 + lm]);
      float gxz = b2f(gxr_[grow * 64 + 16 + lm]);
      float gxn = b2f(gxr_[grow * 64 + 32 + lm]);
      float rg = sigmoidf_(gxr + a0[i] + bhrv);
      float zg = sigmoidf_(gxz + a1[i] + bhzv);
      float ng = tanhf_(gxn + rg * (a2[i] + bhnv));
      float hn = (1.f - zg) * ng + zg * hprev[i];
      hprev[i] = hn;
      // plain store: dirty in our L2; published by the release fence below
      hnext[(size_t)grow * 1024 + c0 + lm] = f2b(hn);
    }

    // ---- stage gx(t+1) into the other LDS buffer
    if (havepf) {
      u16* gxw = gx + ((t + 1) & 1) * 4096;
      *(uint4*)(gxw + sr_r * 64 + sr_s * 16) = pf0;
      *(uint4*)(gxw + sr_r * 64 + sr_s * 16 + 8) = pf1;
    }

    // ---- 64-WG barrier with release/acquire cache maintenance.
    // syncthreads drains vmcnt => all 4 waves' h stores are in L2 before the
    // release fence (buffer_wbl2) publishes them to IF.
    __syncthreads();
    if (tid == 0) {
      __builtin_amdgcn_fence(__ATOMIC_RELEASE, "agent");   // buffer_wbl2
      __hip_atomic_fetch_add(&bars[barid], 1, __ATOMIC_RELAXED, __HIP_MEMORY_SCOPE_AGENT);
      const int tgt = (t + 1) * 64;
      while (__hip_atomic_load(&bars[barid], __ATOMIC_RELAXED, __HIP_MEMORY_SCOPE_AGENT) < tgt) {
        __builtin_amdgcn_s_sleep(1);
      }
      __builtin_amdgcn_fence(__ATOMIC_ACQUIRE, "agent");   // buffer_inv (L1+L2)
    }
    __syncthreads();
  }

  // ---- final output: out[0, b, d*1024 + c]  (f32)
#pragma unroll
  for (int i = 0; i < 4; ++i) {
    int b = g * 64 + wv * 16 + lk * 4 + i;
    out[(size_t)b * 2048 + d * 1024 + c0 + lm] = hprev[i];
  }
}

extern "C" void kernel_launch(void* const* d_in, const int* in_sizes, int n_in,
                              void* d_out, int out_size, void* d_ws, size_t ws_size,
                              hipStream_t stream)
{
  const int*   seq  = (const int*)d_in[0];
  const float* emb  = (const float*)d_in[1];
  const float* Wihf = (const float*)d_in[2];
  const float* Whhf = (const float*)d_in[3];
  const float* bihf = (const float*)d_in[4];
  const float* bhhf = (const float*)d_in[5];
  const float* Wihr = (const float*)d_in[6];
  const float* Whhr = (const float*)d_in[7];
  const float* bihr = (const float*)d_in[8];
  const float* bhhr = (const float*)d_in[9];
  float* out = (float*)d_out;

  // workspace layout (u16 units)
  u16* ws = (u16*)d_ws;
  const size_t nE = (size_t)VOCAB * GCOLS;
  const size_t nEmb = (size_t)VOCAB * 1024;
  const size_t nW = (size_t)GCOLS * 1024;
  size_t off = 0;
  u16* Ef     = ws + off; off += nE;
  u16* Er     = ws + off; off += nE;
  u16* emb_b  = ws + off; off += nEmb;
  u16* Wihf_b = ws + off; off += nW;
  u16* Wihr_b = ws + off; off += nW;
  u16* Whhf_b = ws + off; off += nW;
  u16* Whhr_b = ws + off; off += nW;
  u16* hbuf   = ws + off; off += (size_t)2 * 256 * 1024;
  int* bars   = (int*)(ws + off);

  hipMemsetAsync(hbuf, 0, (size_t)2 * 256 * 1024 * sizeof(u16) + 512, stream);

  // Phase 0: f32 -> bf16 copies
  k_cvt<<<dim3((nEmb / 4 + 255) / 256), dim3(256), 0, stream>>>(emb,  emb_b,  (int)nEmb);
  k_cvt<<<dim3((nW   / 4 + 255) / 256), dim3(256), 0, stream>>>(Wihf, Wihf_b, (int)nW);
  k_cvt<<<dim3((nW   / 4 + 255) / 256), dim3(256), 0, stream>>>(Wihr, Wihr_b, (int)nW);
  k_cvt<<<dim3((nW   / 4 + 255) / 256), dim3(256), 0, stream>>>(Whhf, Whhf_b, (int)nW);
  k_cvt<<<dim3((nW   / 4 + 255) / 256), dim3(256), 0, stream>>>(Whhr, Whhr_b, (int)nW);

  // Phase 1: vocab-level input projection tables
  k_gx<<<dim3(48 * 250), dim3(256), 0, stream>>>(emb_b, Wihf_b, bihf, Wihr_b, bihr, Ef, Er);

  // Phase 2: persistent recurrence (1 WG/CU, 256 WGs)
  const int smem = (48 * WHH_STRIDE + 2 * 64 * 64) * sizeof(u16);   // 115,456 B
  hipFuncSetAttribute(reinterpret_cast<const void*>(k_rnn),
                      hipFuncAttributeMaxDynamicSharedMemorySize, smem);
  k_rnn<<<dim3(256), dim3(256), smem, stream>>>(seq, Ef, Er, Whhf_b, bhhf, Whhr_b, bhhr,
                                                hbuf, bars, out);
}

// Round 2
// 4894.822 us; speedup vs baseline: 1.4915x; 1.4915x over previous
//
#include <hip/hip_runtime.h>
#include <stdint.h>

#define LSEQ  512
#define VOCAB 32000
#define GCOLS 3072               // 3*H2 per direction
#define WHH_STRIDE 1032          // 1024 + 8 halfs pad (16B)

typedef __attribute__((ext_vector_type(8))) short short8;
typedef __attribute__((ext_vector_type(4))) float f32x4;
typedef unsigned short u16;
typedef unsigned int   u32;
typedef unsigned long long u64;

__device__ __forceinline__ float b2f(u16 u) {
  union { u32 i; float f; } x; x.i = ((u32)u) << 16; return x.f;
}
__device__ __forceinline__ u16 f2b(float f) {
  union { float f; u32 i; } x; x.f = f;
  u32 r = (x.i + 0x7fffu + ((x.i >> 16) & 1u)) >> 16;
  return (u16)r;
}
__device__ __forceinline__ void load_lds16(const void* g, void* l) {
  __builtin_amdgcn_global_load_lds(
      (const __attribute__((address_space(1))) void*)g,
      (__attribute__((address_space(3))) void*)l, 16, 0, 0);
}
__device__ __forceinline__ float sigmoidf_(float x) {
  return __builtin_amdgcn_rcpf(1.f + __expf(-x));
}
__device__ __forceinline__ float tanhf_(float x) {
  x = fminf(fmaxf(x, -30.f), 30.f);
  float e = __expf(2.f * x);
  return (e - 1.f) * __builtin_amdgcn_rcpf(e + 1.f);
}

// ---------------------------------------------------------------------------
// Phase 0: f32 -> bf16 (RNE) bulk conversion into workspace.
// ---------------------------------------------------------------------------
__global__ __launch_bounds__(256) void k_cvt(const float* __restrict__ s,
                                             u16* __restrict__ d, int n) {
  int i = (blockIdx.x * 256 + threadIdx.x) * 4;
  if (i >= n) return;
  float4 v = *(const float4*)(s + i);
  u32 lo = (u32)f2b(v.x) | ((u32)f2b(v.y) << 16);
  u32 hi = (u32)f2b(v.z) | ((u32)f2b(v.w) << 16);
  uint2 pk; pk.x = lo; pk.y = hi;
  *(uint2*)(d + i) = pk;
}

// ---------------------------------------------------------------------------
// Phase 1: E'[v, g] = sum_k emb[v,k] * Wih[g,k] + bih[g]  (both dirs).
// Unchanged (verified correct).
// ---------------------------------------------------------------------------
__global__ __launch_bounds__(256) void k_gx(
    const u16* __restrict__ emb,
    const u16* __restrict__ Wf, const float* __restrict__ bf,
    const u16* __restrict__ Wr, const float* __restrict__ br,
    u16* __restrict__ Ef, u16* __restrict__ Er)
{
  __shared__ u16 lA[128 * 64];
  __shared__ u16 lB[128 * 64];
  const int bid = blockIdx.x;
  const int mt = bid % 48;
  const int nt = bid / 48;
  const u16*   W    = (mt < 24) ? Wf : Wr;
  const float* bias = (mt < 24) ? bf : br;
  u16*         Eo   = (mt < 24) ? Ef : Er;
  const int m0 = (mt < 24 ? mt : mt - 24) * 128;
  const int n0 = nt * 128;
  const int tid = threadIdx.x;
  const int lane = tid & 63, wv = tid >> 6;
  const int wA = wv & 1, wB = wv >> 1;
  const int lm = lane & 15, lk = lane >> 4;

  f32x4 acc[4][4];
#pragma unroll
  for (int i = 0; i < 4; ++i)
#pragma unroll
    for (int j = 0; j < 4; ++j) acc[i][j] = (f32x4){0.f, 0.f, 0.f, 0.f};

  for (int k0 = 0; k0 < 1024; k0 += 64) {
#pragma unroll
    for (int it = 0; it < 4; ++it) {
      int slot = it * 256 + tid;
      int row = slot >> 3, seg = slot & 7;
      load_lds16(W + (size_t)(m0 + row) * 1024 + k0 + seg * 8,
                 lA + (size_t)(it * 256 + wv * 64) * 8);
      load_lds16(emb + (size_t)(n0 + row) * 1024 + k0 + seg * 8,
                 lB + (size_t)(it * 256 + wv * 64) * 8);
    }
    __syncthreads();
#pragma unroll
    for (int kc = 0; kc < 2; ++kc) {
      short8 af[4], bfr[4];
#pragma unroll
      for (int i = 0; i < 4; ++i)
        af[i] = *(const short8*)&lA[(64 * wA + 16 * i + lm) * 64 + kc * 32 + lk * 8];
#pragma unroll
      for (int j = 0; j < 4; ++j)
        bfr[j] = *(const short8*)&lB[(64 * wB + 16 * j + lm) * 64 + kc * 32 + lk * 8];
#pragma unroll
      for (int i = 0; i < 4; ++i)
#pragma unroll
        for (int j = 0; j < 4; ++j)
          acc[i][j] = __builtin_amdgcn_mfma_f32_16x16x32_bf16(af[i], bfr[j], acc[i][j], 0, 0, 0);
    }
    __syncthreads();
  }

#pragma unroll
  for (int i = 0; i < 4; ++i) {
    int gcol0 = m0 + 64 * wA + 16 * i + lk * 4;
    const float* bp = bias + gcol0;
    float b0 = bp[0], b1 = bp[1], b2_ = bp[2], b3 = bp[3];
#pragma unroll
    for (int j = 0; j < 4; ++j) {
      int vrow = n0 + 64 * wB + 16 * j + lm;
      f32x4 v = acc[i][j];
      u32 lo = (u32)f2b(v.x + b0) | ((u32)f2b(v.y + b1) << 16);
      u32 hi = (u32)f2b(v.z + b2_) | ((u32)f2b(v.w + b3) << 16);
      uint2 pk; pk.x = lo; pk.y = hi;
      *(uint2*)(Eo + (size_t)vrow * GCOLS + gcol0) = pk;
    }
  }
}

// ---------------------------------------------------------------------------
// Phase 2: persistent GRU recurrence. R0 semantics (zero cache maintenance):
//  - h stores: relaxed agent-scope atomic u16 (write-through to IF; no dirty
//    L2 anywhere => no wbl2 needed; __syncthreads' vmcnt(0) drains them)
//  - h loads:  16B global_load_dwordx4 sc1 (L1+L2 bypass, IF-fresh — same
//    encoding the compiler emits for agent-scope atomic loads, but 2x fewer
//    requests than R0's 8B atomics: the h broadcast was request-rate-bound).
//    Batch-issued (32 in flight), single vmcnt(0) + sched_barrier(0) before
//    the MFMA consumes them (rule: compiler may hoist MFMA past asm waitcnt).
//  - barrier:  relaxed agent add + relaxed agent spin load (no fences)
//  - gx double-buffered in LDS; E(t+1) prefetched into regs at top of step.
// ---------------------------------------------------------------------------
__global__ __launch_bounds__(256, 1) void k_rnn(
    const int* __restrict__ seq,
    const u16* __restrict__ Ef, const u16* __restrict__ Er,
    const u16* __restrict__ Whf, const float* __restrict__ bhf,
    const u16* __restrict__ Whr, const float* __restrict__ bhr,
    u16* __restrict__ hbuf, int* __restrict__ bars,
    float* __restrict__ out)
{
  extern __shared__ u16 lds[];
  u16* whh = lds;                           // [48][WHH_STRIDE]
  u16* gx  = lds + 48 * WHH_STRIDE;         // [2][64][64] double buffer
  const int bid = blockIdx.x;
  const int d = bid & 1, g = (bid >> 1) & 1, cw = bid >> 2;
  const int c0 = cw * 16;
  const int barid = (bid & 3) * 32;         // 128B-separated counters
  const u16*   Wh = d ? Whr : Whf;
  const float* bh = d ? bhr : bhf;
  const u16*   E  = d ? Er  : Ef;
  const int tid = threadIdx.x;
  const int lane = tid & 63, wv = tid >> 6;
  const int lm = lane & 15, lk = lane >> 4;

  // --- stage Whh slice: LDS row gate*16+jc <- Wh[gate*1024 + c0 + jc][:]
  for (int it = 0; it < 24; ++it) {
    int idx = it * 256 + tid;
    int row = idx >> 7, q = idx & 127;
    int gate = row >> 4, jc = row & 15;
    uint4 v = *(const uint4*)(Wh + (size_t)((gate << 10) + c0 + jc) * 1024 + q * 8);
    *(uint4*)(whh + (size_t)row * WHH_STRIDE + q * 8) = v;
  }
  const float bhrv = bh[c0 + lm];
  const float bhzv = bh[1024 + c0 + lm];
  const float bhnv = bh[2048 + c0 + lm];

  float hprev[4] = {0.f, 0.f, 0.f, 0.f};
  const int rowA = g * 64 + wv * 16 + lm;

  const int sr_r = tid / 3;                 // gx staging: threads 0..191
  const int sr_s = tid - sr_r * 3;
  const int sr_b = g * 64 + sr_r;
  const int sr_seqrow = d ? (127 - sr_b) : sr_b;
  const bool stager = (tid < 192);

  // prime gx(0) into buffer 0
  if (stager) {
    int tok = seq[sr_seqrow * LSEQ + 0];
    const u16* src = E + (size_t)tok * GCOLS + sr_s * 1024 + c0;
    uint4 v0 = *(const uint4*)src;
    uint4 v1 = *(const uint4*)(src + 8);
    *(uint4*)(gx + sr_r * 64 + sr_s * 16) = v0;
    *(uint4*)(gx + sr_r * 64 + sr_s * 16 + 8) = v1;
  }
  __syncthreads();   // whh + gx(0) ready

  const u16* whp0 = whh + (size_t)lm * WHH_STRIDE + lk * 8;
  const u16* whp1 = whh + (size_t)(16 + lm) * WHH_STRIDE + lk * 8;
  const u16* whp2 = whh + (size_t)(32 + lm) * WHH_STRIDE + lk * 8;

  for (int t = 0; t < LSEQ; ++t) {
    // ---- prefetch E(t+1) into regs (latency overlaps h-loads + MFMA)
    uint4 pf0, pf1;
    const bool havepf = stager && (t + 1 < LSEQ);
    if (havepf) {
      int tok = seq[sr_seqrow * LSEQ + t + 1];
      const u16* src = E + (size_t)tok * GCOLS + sr_s * 1024 + c0;
      pf0 = *(const uint4*)src;
      pf1 = *(const uint4*)(src + 8);
    }

    // ---- h(t) loads: 16B L1/L2-bypass loads (IF-fresh), batch-issued.
    const u16* hb = hbuf + ((size_t)((t & 1) * 256 + d * 128 + rowA)) * 1024 + lk * 8;
    uint4 hv[32];
#pragma unroll
    for (int kc = 0; kc < 32; ++kc) {
      asm volatile("global_load_dwordx4 %0, %1, off sc1"
                   : "=v"(hv[kc])
                   : "v"(hb + kc * 32)
                   : "memory");
    }
    asm volatile("s_waitcnt vmcnt(0)" ::: "memory");
    __builtin_amdgcn_sched_barrier(0);

    // ---- gh = h @ Whh_slice^T
    f32x4 a0 = (f32x4){0.f,0.f,0.f,0.f};
    f32x4 a1 = (f32x4){0.f,0.f,0.f,0.f};
    f32x4 a2 = (f32x4){0.f,0.f,0.f,0.f};
#pragma unroll
    for (int kc = 0; kc < 32; ++kc) {
      union { uint4 v; short8 s; } u;
      u.v = hv[kc];
      short8 av  = u.s;
      short8 b0v = *(const short8*)(whp0 + kc * 32);
      short8 b1v = *(const short8*)(whp1 + kc * 32);
      short8 b2v = *(const short8*)(whp2 + kc * 32);
      a0 = __builtin_amdgcn_mfma_f32_16x16x32_bf16(av, b0v, a0, 0, 0, 0);
      a1 = __builtin_amdgcn_mfma_f32_16x16x32_bf16(av, b1v, a1, 0, 0, 0);
      a2 = __builtin_amdgcn_mfma_f32_16x16x32_bf16(av, b2v, a2, 0, 0, 0);
    }

    // ---- gates + state update (C layout: col=c0+lm, row=lk*4+i)
    const u16* gxr_ = gx + (t & 1) * 4096;
    u16* hnext = hbuf + ((size_t)(((t + 1) & 1) * 256 + d * 128 + g * 64)) * 1024;
#pragma unroll
    for (int i = 0; i < 4; ++i) {
      int grow = wv * 16 + lk * 4 + i;
      float gxr = b2f(gxr_[grow * 64 + lm]);
      float gxz = b2f(gxr_[grow * 64 + 16 + lm]);
      float gxn = b2f(gxr_[grow * 64 + 32 + lm]);
      float rg = sigmoidf_(gxr + a0[i] + bhrv);
      float zg = sigmoidf_(gxz + a1[i] + bhzv);
      float ng = tanhf_(gxn + rg * (a2[i] + bhnv));
      float hn = (1.f - zg) * ng + zg * hprev[i];
      hprev[i] = hn;
      // write-through store to IF (no dirty L2 anywhere)
      __hip_atomic_store(&hnext[(size_t)grow * 1024 + c0 + lm], f2b(hn),
                         __ATOMIC_RELAXED, __HIP_MEMORY_SCOPE_AGENT);
    }

    // ---- stage gx(t+1) into the other LDS buffer
    if (havepf) {
      u16* gxw = gx + ((t + 1) & 1) * 4096;
      *(uint4*)(gxw + sr_r * 64 + sr_s * 16) = pf0;
      *(uint4*)(gxw + sr_r * 64 + sr_s * 16 + 8) = pf1;
    }

    // ---- 64-WG barrier (syncthreads drains vmcnt => h stores are at IF)
    __syncthreads();
    if (tid == 0) {
      __hip_atomic_fetch_add(&bars[barid], 1, __ATOMIC_RELAXED, __HIP_MEMORY_SCOPE_AGENT);
      const int tgt = (t + 1) * 64;
      while (__hip_atomic_load(&bars[barid], __ATOMIC_RELAXED, __HIP_MEMORY_SCOPE_AGENT) < tgt) {
        __builtin_amdgcn_s_sleep(1);
      }
    }
    __syncthreads();
  }

  // ---- final output: out[0, b, d*1024 + c]  (f32)
#pragma unroll
  for (int i = 0; i < 4; ++i) {
    int b = g * 64 + wv * 16 + lk * 4 + i;
    out[(size_t)b * 2048 + d * 1024 + c0 + lm] = hprev[i];
  }
}

extern "C" void kernel_launch(void* const* d_in, const int* in_sizes, int n_in,
                              void* d_out, int out_size, void* d_ws, size_t ws_size,
                              hipStream_t stream)
{
  const int*   seq  = (const int*)d_in[0];
  const float* emb  = (const float*)d_in[1];
  const float* Wihf = (const float*)d_in[2];
  const float* Whhf = (const float*)d_in[3];
  const float* bihf = (const float*)d_in[4];
  const float* bhhf = (const float*)d_in[5];
  const float* Wihr = (const float*)d_in[6];
  const float* Whhr = (const float*)d_in[7];
  const float* bihr = (const float*)d_in[8];
  const float* bhhr = (const float*)d_in[9];
  float* out = (float*)d_out;

  // workspace layout (u16 units)
  u16* ws = (u16*)d_ws;
  const size_t nE = (size_t)VOCAB * GCOLS;
  const size_t nEmb = (size_t)VOCAB * 1024;
  const size_t nW = (size_t)GCOLS * 1024;
  size_t off = 0;
  u16* Ef     = ws + off; off += nE;
  u16* Er     = ws + off; off += nE;
  u16* emb_b  = ws + off; off += nEmb;
  u16* Wihf_b = ws + off; off += nW;
  u16* Wihr_b = ws + off; off += nW;
  u16* Whhf_b = ws + off; off += nW;
  u16* Whhr_b = ws + off; off += nW;
  u16* hbuf   = ws + off; off += (size_t)2 * 256 * 1024;
  int* bars   = (int*)(ws + off);

  hipMemsetAsync(hbuf, 0, (size_t)2 * 256 * 1024 * sizeof(u16) + 512, stream);

  // Phase 0: f32 -> bf16 copies
  k_cvt<<<dim3((nEmb / 4 + 255) / 256), dim3(256), 0, stream>>>(emb,  emb_b,  (int)nEmb);
  k_cvt<<<dim3((nW   / 4 + 255) / 256), dim3(256), 0, stream>>>(Wihf, Wihf_b, (int)nW);
  k_cvt<<<dim3((nW   / 4 + 255) / 256), dim3(256), 0, stream>>>(Wihr, Wihr_b, (int)nW);
  k_cvt<<<dim3((nW   / 4 + 255) / 256), dim3(256), 0, stream>>>(Whhf, Whhf_b, (int)nW);
  k_cvt<<<dim3((nW   / 4 + 255) / 256), dim3(256), 0, stream>>>(Whhr, Whhr_b, (int)nW);

  // Phase 1: vocab-level input projection tables
  k_gx<<<dim3(48 * 250), dim3(256), 0, stream>>>(emb_b, Wihf_b, bihf, Wihr_b, bihr, Ef, Er);

  // Phase 2: persistent recurrence (1 WG/CU, 256 WGs)
  const int smem = (48 * WHH_STRIDE + 2 * 64 * 64) * sizeof(u16);   // 115,456 B
  hipFuncSetAttribute(reinterpret_cast<const void*>(k_rnn),
                      hipFuncAttributeMaxDynamicSharedMemorySize, smem);
  k_rnn<<<dim3(256), dim3(256), smem, stream>>>(seq, Ef, Er, Whhf_b, bhhf, Whhr_b, bhhr,
                                                hbuf, bars, out);
}

// Round 3
// 3224.320 us; speedup vs baseline: 2.2642x; 1.5181x over previous
//
#include <hip/hip_runtime.h>
#include <stdint.h>

#define LSEQ  512
#define VOCAB 32000
#define GCOLS 3072               // 3*H2 per direction
#define GXS   104                // gx LDS row stride (u16), padded
#define NW    32                 // WGs (col-slices) per group

typedef __attribute__((ext_vector_type(8))) short short8;
typedef __attribute__((ext_vector_type(4))) float f32x4;
typedef unsigned short u16;
typedef unsigned int   u32;
typedef unsigned long long u64;

__device__ __forceinline__ float b2f(u16 u) {
  union { u32 i; float f; } x; x.i = ((u32)u) << 16; return x.f;
}
__device__ __forceinline__ u16 f2b(float f) {
  union { float f; u32 i; } x; x.f = f;
  u32 r = (x.i + 0x7fffu + ((x.i >> 16) & 1u)) >> 16;
  return (u16)r;
}
__device__ __forceinline__ void load_lds16(const void* g, void* l) {
  __builtin_amdgcn_global_load_lds(
      (const __attribute__((address_space(1))) void*)g,
      (__attribute__((address_space(3))) void*)l, 16, 0, 0);
}
__device__ __forceinline__ float sigmoidf_(float x) {
  return __builtin_amdgcn_rcpf(1.f + __expf(-x));
}
__device__ __forceinline__ float tanhf_(float x) {
  x = fminf(fmaxf(x, -30.f), 30.f);
  float e = __expf(2.f * x);
  return (e - 1.f) * __builtin_amdgcn_rcpf(e + 1.f);
}

// ---------------------------------------------------------------------------
// Phase 0: f32 -> bf16 (RNE) bulk conversion into workspace.
// ---------------------------------------------------------------------------
__global__ __launch_bounds__(256) void k_cvt(const float* __restrict__ s,
                                             u16* __restrict__ d, int n) {
  int i = (blockIdx.x * 256 + threadIdx.x) * 4;
  if (i >= n) return;
  float4 v = *(const float4*)(s + i);
  u32 lo = (u32)f2b(v.x) | ((u32)f2b(v.y) << 16);
  u32 hi = (u32)f2b(v.z) | ((u32)f2b(v.w) << 16);
  uint2 pk; pk.x = lo; pk.y = hi;
  *(uint2*)(d + i) = pk;
}

// ---------------------------------------------------------------------------
// Phase 1: E'[v, g] = sum_k emb[v,k] * Wih[g,k] + bih[g]  (both dirs).
// Unchanged (verified correct).
// ---------------------------------------------------------------------------
__global__ __launch_bounds__(256) void k_gx(
    const u16* __restrict__ emb,
    const u16* __restrict__ Wf, const float* __restrict__ bf,
    const u16* __restrict__ Wr, const float* __restrict__ br,
    u16* __restrict__ Ef, u16* __restrict__ Er)
{
  __shared__ u16 lA[128 * 64];
  __shared__ u16 lB[128 * 64];
  const int bid = blockIdx.x;
  const int mt = bid % 48;
  const int nt = bid / 48;
  const u16*   W    = (mt < 24) ? Wf : Wr;
  const float* bias = (mt < 24) ? bf : br;
  u16*         Eo   = (mt < 24) ? Ef : Er;
  const int m0 = (mt < 24 ? mt : mt - 24) * 128;
  const int n0 = nt * 128;
  const int tid = threadIdx.x;
  const int lane = tid & 63, wv = tid >> 6;
  const int wA = wv & 1, wB = wv >> 1;
  const int lm = lane & 15, lk = lane >> 4;

  f32x4 acc[4][4];
#pragma unroll
  for (int i = 0; i < 4; ++i)
#pragma unroll
    for (int j = 0; j < 4; ++j) acc[i][j] = (f32x4){0.f, 0.f, 0.f, 0.f};

  for (int k0 = 0; k0 < 1024; k0 += 64) {
#pragma unroll
    for (int it = 0; it < 4; ++it) {
      int slot = it * 256 + tid;
      int row = slot >> 3, seg = slot & 7;
      load_lds16(W + (size_t)(m0 + row) * 1024 + k0 + seg * 8,
                 lA + (size_t)(it * 256 + wv * 64) * 8);
      load_lds16(emb + (size_t)(n0 + row) * 1024 + k0 + seg * 8,
                 lB + (size_t)(it * 256 + wv * 64) * 8);
    }
    __syncthreads();
#pragma unroll
    for (int kc = 0; kc < 2; ++kc) {
      short8 af[4], bfr[4];
#pragma unroll
      for (int i = 0; i < 4; ++i)
        af[i] = *(const short8*)&lA[(64 * wA + 16 * i + lm) * 64 + kc * 32 + lk * 8];
#pragma unroll
      for (int j = 0; j < 4; ++j)
        bfr[j] = *(const short8*)&lB[(64 * wB + 16 * j + lm) * 64 + kc * 32 + lk * 8];
#pragma unroll
      for (int i = 0; i < 4; ++i)
#pragma unroll
        for (int j = 0; j < 4; ++j)
          acc[i][j] = __builtin_amdgcn_mfma_f32_16x16x32_bf16(af[i], bfr[j], acc[i][j], 0, 0, 0);
    }
    __syncthreads();
  }

#pragma unroll
  for (int i = 0; i < 4; ++i) {
    int gcol0 = m0 + 64 * wA + 16 * i + lk * 4;
    const float* bp = bias + gcol0;
    float b0 = bp[0], b1 = bp[1], b2_ = bp[2], b3 = bp[3];
#pragma unroll
    for (int j = 0; j < 4; ++j) {
      int vrow = n0 + 64 * wB + 16 * j + lm;
      f32x4 v = acc[i][j];
      u32 lo = (u32)f2b(v.x + b0) | ((u32)f2b(v.y + b1) << 16);
      u32 hi = (u32)f2b(v.z + b2_) | ((u32)f2b(v.w + b3) << 16);
      uint2 pk; pk.x = lo; pk.y = hi;
      *(uint2*)(Eo + (size_t)vrow * GCOLS + gcol0) = pk;
    }
  }
}

// ---------------------------------------------------------------------------
// Phase 2: persistent GRU recurrence — XCD-LOCAL exchange design.
//  * 8 independent groups (d in {f,r}) x (batch quarter of 32 rows), each
//    pinned to ONE XCD via HW_REG_XCC_ID + per-XCD ticket (self-placement, no
//    reliance on a bid->XCD mapping). 32 WGs/group, 32 output cols each.
//  * h exchange stays in the XCD's L2: plain write-back stores (LDS-gathered,
//    16B coalesced), sc0 loads (SE scope: bypass L1, hit L2). No IF traffic.
//  * Whh lives in VGPRs (48 x 16B per lane); K is split across the 4 waves
//    (256 each) and partials are reduced through LDS. No ds_read in MFMA loop.
//  * h loads software-pipelined under MFMA with counted vmcnt; every wave
//    issues exactly 18 VMEM ops per step so the counts are uniform.
//  * barrier: per-group agent(IF)-scope counter, memset each launch (IF is
//    memory-side => DMA-coherent). h buffers are NEVER memset (L2-dirty lines
//    are the truth); h(0) is zeroed in-kernel before barrier #0.
// ---------------------------------------------------------------------------
__global__ __launch_bounds__(256, 1) void k_rnn(
    const int* __restrict__ seq,
    const u16* __restrict__ Ef, const u16* __restrict__ Er,
    const u16* __restrict__ Whf, const float* __restrict__ bhf,
    const u16* __restrict__ Whr, const float* __restrict__ bhr,
    u16* __restrict__ hbuf, int* __restrict__ ctrl,
    float* __restrict__ out)
{
  extern __shared__ u16 lds[];
  u16*   gx   = lds;                               // [2][32][GXS]
  f32x4* redv = (f32x4*)(lds + 2 * 32 * GXS);      // [4 dst][4 src][64][5]
  u16*   outt = (u16*)(redv + 4 * 4 * 64 * 5);     // [32][32]
  int*   bc   = (int*)(outt + 32 * 32);            // {grp, rank} broadcast

  int* bars    = ctrl;         // [8][32] ints (128B apart)
  int* tickets = ctrl + 256;   // [8]

  const int tid = threadIdx.x;
  const int lane = tid & 63, wv = tid >> 6;
  const int lm = lane & 15, lk = lane >> 4;

  // ---- self-placement: which XCD am I on?
  if (tid == 0) {
    u32 xcc;
    asm volatile("s_getreg_b32 %0, hwreg(20, 0, 4)" : "=s"(xcc));  // HW_REG_XCC_ID
    xcc &= 7u;
    int rk = __hip_atomic_fetch_add(&tickets[xcc], 1, __ATOMIC_RELAXED,
                                    __HIP_MEMORY_SCOPE_AGENT);
    bc[0] = (int)xcc;
    bc[1] = rk;
  }
  __syncthreads();
  const int grp  = bc[0];
  const int rank = bc[1];
  if (rank >= NW) return;                  // imbalance safety valve

  const int d  = grp & 1;
  const int g3 = grp >> 1;                 // batch quarter (32 rows)
  const int c0g = rank * 32;               // this WG's 32 output cols

  const u16*   Wh = d ? Whr : Whf;
  const float* bh = d ? bhr : bhf;
  const u16*   E  = d ? Er  : Ef;

  const int rtm = wv >> 1, ctlm = wv & 1;  // gate-phase ownership

  // ---- Whh fragments -> registers (held for the whole kernel)
  short8 wf[6][8];
#pragma unroll
  for (int ct = 0; ct < 6; ++ct) {
    const int gate = ct >> 1, ctl = ct & 1;
    const u16* wp = Wh + (size_t)(gate * 1024 + c0g + ctl * 16 + lm) * 1024
                       + wv * 256 + lk * 8;
#pragma unroll
    for (int kcs = 0; kcs < 8; ++kcs)
      wf[ct][kcs] = *(const short8*)(wp + kcs * 32);
  }

  const int jg = c0g + ctlm * 16 + lm;
  const float bhrv = bh[jg], bhzv = bh[1024 + jg], bhnv = bh[2048 + jg];

  // h layout: hbuf[(buf*2 + d)*128 + row][1024]
  u16* hb0 = hbuf + ((size_t)(0 * 2 + d) * 128 + g3 * 32) * 1024;
  u16* hb1 = hbuf + ((size_t)(1 * 2 + d) * 128 + g3 * 32) * 1024;

  // ---- zero h(0) tile (buf0): 32 rows x 32 cols, plain stores -> local L2
  if (tid < 128) {
    const int zr = tid >> 2, zs = tid & 3;
    uint4 zz = make_uint4(0u, 0u, 0u, 0u);
    *(uint4*)(hb0 + (size_t)zr * 1024 + c0g + zs * 8) = zz;
  }

  // ---- gx stagers: 192 threads, each 32B of E'(token)
  const bool stager = (tid < 192);
  const int sr_row = tid / 6, sr_piece = tid - sr_row * 6;
  const int sgate = sr_piece >> 1, sctl = sr_piece & 1;
  const int sb = g3 * 32 + sr_row;
  const int sseq = d ? (127 - sb) : sb;
  const size_t ecol = (size_t)sgate * 1024 + c0g + sctl * 16;

  if (stager) {
    int tok = seq[sseq * LSEQ + 0];
    const u16* src = E + (size_t)tok * GCOLS + ecol;
    uint4 v0 = *(const uint4*)src;
    uint4 v1 = *(const uint4*)(src + 8);
    u16* gw = gx + sr_row * GXS + sr_piece * 16;
    *(uint4*)gw = v0;
    *(uint4*)(gw + 8) = v1;
  }
  __syncthreads();   // gx(0) staged; own zeros drained (vmcnt0 at barrier)

  int bcount = 0;
  const int barid = grp * 32;

  // barrier #0: all zeros of h(0) visible group-wide (L2)
  ++bcount;
  if (tid == 0) {
    __hip_atomic_fetch_add(&bars[barid], 1, __ATOMIC_RELAXED, __HIP_MEMORY_SCOPE_AGENT);
    const int tgt = bcount * NW;
    while (__hip_atomic_load(&bars[barid], __ATOMIC_RELAXED, __HIP_MEMORY_SCOPE_AGENT) < tgt)
      __builtin_amdgcn_s_sleep(1);
  }
  __syncthreads();

  float hprev[4] = {0.f, 0.f, 0.f, 0.f};
  const int hro = lm * 1024 + wv * 256 + lk * 8;   // row lm, wave K-quarter

#define MFMA_STEP(K, WSTR)                                                     \
  do {                                                                         \
    asm volatile("s_waitcnt vmcnt(" WSTR ")" ::: "memory");                    \
    __builtin_amdgcn_sched_barrier(0);                                         \
    union { uint4 v; short8 s; } ua0, ua1;                                     \
    ua0.v = hv[0][K]; ua1.v = hv[1][K];                                        \
    _Pragma("unroll")                                                          \
    for (int ct = 0; ct < 6; ++ct) {                                           \
      acc[0][ct] = __builtin_amdgcn_mfma_f32_16x16x32_bf16(ua0.s, wf[ct][K],   \
                                                           acc[0][ct], 0, 0, 0); \
      acc[1][ct] = __builtin_amdgcn_mfma_f32_16x16x32_bf16(ua1.s, wf[ct][K],   \
                                                           acc[1][ct], 0, 0, 0); \
    }                                                                          \
  } while (0)

  for (int t = 0; t < LSEQ; ++t) {
    const u16* hrd = (t & 1) ? hb1 : hb0;
    u16*       hwr = (t & 1) ? hb0 : hb1;

    // ---- token for t+1 FIRST (its waitcnt lands before the h-load batch)
    const u16* esrc = hrd;     // harmless default for wave 3
    if (stager) {
      const int tp = (t + 1 < LSEQ) ? (t + 1) : (LSEQ - 1);
      int tok = seq[sseq * LSEQ + tp];
      esrc = E + (size_t)tok * GCOLS + ecol;
    }

    // ---- issue 16 h loads (sc0: bypass L1, served by XCD L2)
    uint4 hv[2][8];
#pragma unroll
    for (int kcs = 0; kcs < 8; ++kcs) {
#pragma unroll
      for (int rt = 0; rt < 2; ++rt) {
        asm volatile("global_load_dwordx4 %0, %1, off sc0"
                     : "=v"(hv[rt][kcs])
                     : "v"(hrd + (size_t)rt * 16384 + hro + kcs * 32)
                     : "memory");
      }
    }
    // ---- 2 more VMEM ops on EVERY wave (E prefetch / dummies) => uniform 18
    uint4 pf0, pf1;
    if (stager) {
      asm volatile("global_load_dwordx4 %0, %1, off" : "=v"(pf0) : "v"(esrc) : "memory");
      asm volatile("global_load_dwordx4 %0, %1, off" : "=v"(pf1) : "v"(esrc + 8) : "memory");
    } else {
      asm volatile("global_load_dwordx4 %0, %1, off sc0" : "=v"(pf0) : "v"(hrd + hro) : "memory");
      asm volatile("global_load_dwordx4 %0, %1, off sc0" : "=v"(pf1) : "v"(hrd + hro) : "memory");
    }

    // ---- gh partials: wave's K-quarter, counted-vmcnt pipeline
    f32x4 acc[2][6];
#pragma unroll
    for (int rt = 0; rt < 2; ++rt)
#pragma unroll
      for (int ct = 0; ct < 6; ++ct) acc[rt][ct] = (f32x4){0.f, 0.f, 0.f, 0.f};

    MFMA_STEP(0, "16");
    MFMA_STEP(1, "14");
    MFMA_STEP(2, "12");
    MFMA_STEP(3, "10");
    MFMA_STEP(4, "8");
    MFMA_STEP(5, "6");
    MFMA_STEP(6, "4");
    MFMA_STEP(7, "2");

    // ---- cross-wave K reduction through LDS
#pragma unroll
    for (int rt = 0; rt < 2; ++rt)
#pragma unroll
      for (int ct = 0; ct < 6; ++ct) {
        const int wq = rt * 2 + (ct & 1);
        const int gate = ct >> 1;
        const int sl = (wv - wq) & 3;
        redv[(size_t)((wq * 4 + sl) * 64 + lane) * 5 + gate] = acc[rt][ct];
      }
    __syncthreads();
    f32x4 tot[3];
#pragma unroll
    for (int gate = 0; gate < 3; ++gate) {
      f32x4 v = redv[(size_t)((wv * 4 + 0) * 64 + lane) * 5 + gate];
#pragma unroll
      for (int sl = 1; sl < 4; ++sl)
        v = v + redv[(size_t)((wv * 4 + sl) * 64 + lane) * 5 + gate];
      tot[gate] = v;
    }

    // ---- gates + state update (rows rtm*16+lk*4+i, col ctlm*16+lm)
    const u16* gxr_ = gx + (t & 1) * (32 * GXS);
#pragma unroll
    for (int i = 0; i < 4; ++i) {
      const int rl = rtm * 16 + lk * 4 + i;
      const float gr = b2f(gxr_[rl * GXS +      ctlm * 16 + lm]);
      const float gz = b2f(gxr_[rl * GXS + 32 + ctlm * 16 + lm]);
      const float gn = b2f(gxr_[rl * GXS + 64 + ctlm * 16 + lm]);
      const float rg = sigmoidf_(gr + tot[0][i] + bhrv);
      const float zg = sigmoidf_(gz + tot[1][i] + bhzv);
      const float ng = tanhf_(gn + rg * (tot[2][i] + bhnv));
      const float hn = (1.f - zg) * ng + zg * hprev[i];
      hprev[i] = hn;
      outt[rl * 32 + ctlm * 16 + lm] = f2b(hn);
    }

    // ---- stage gx(t+1) (needs E prefetch data)
    asm volatile("s_waitcnt vmcnt(0)" ::: "memory");
    __builtin_amdgcn_sched_barrier(0);
    if (stager && (t + 1 < LSEQ)) {
      u16* gw = gx + ((t + 1) & 1) * (32 * GXS) + sr_row * GXS + sr_piece * 16;
      *(uint4*)gw = pf0;
      *(uint4*)(gw + 8) = pf1;
    }
    __syncthreads();   // outt + gx(t+1) ready

    // ---- h(t+1) store: coalesced 16B plain stores -> local L2
    if (tid < 128) {
      const int zr = tid >> 2, zs = tid & 3;
      uint4 v = *(const uint4*)(outt + zr * 32 + zs * 8);
      *(uint4*)(hwr + (size_t)zr * 1024 + c0g + zs * 8) = v;
    }

    // ---- group barrier (stores drained by syncthreads' vmcnt(0))
    __syncthreads();
    ++bcount;
    if (tid == 0) {
      __hip_atomic_fetch_add(&bars[barid], 1, __ATOMIC_RELAXED, __HIP_MEMORY_SCOPE_AGENT);
      const int tgt = bcount * NW;
      while (__hip_atomic_load(&bars[barid], __ATOMIC_RELAXED, __HIP_MEMORY_SCOPE_AGENT) < tgt)
        __builtin_amdgcn_s_sleep(1);
    }
    __syncthreads();
  }

  // ---- final output: out[0, b, d*1024 + c]  (f32)
#pragma unroll
  for (int i = 0; i < 4; ++i) {
    const int rl = rtm * 16 + lk * 4 + i;
    const int b = g3 * 32 + rl;
    out[(size_t)b * 2048 + d * 1024 + c0g + ctlm * 16 + lm] = hprev[i];
  }
#undef MFMA_STEP
}

extern "C" void kernel_launch(void* const* d_in, const int* in_sizes, int n_in,
                              void* d_out, int out_size, void* d_ws, size_t ws_size,
                              hipStream_t stream)
{
  const int*   seq  = (const int*)d_in[0];
  const float* emb  = (const float*)d_in[1];
  const float* Wihf = (const float*)d_in[2];
  const float* Whhf = (const float*)d_in[3];
  const float* bihf = (const float*)d_in[4];
  const float* bhhf = (const float*)d_in[5];
  const float* Wihr = (const float*)d_in[6];
  const float* Whhr = (const float*)d_in[7];
  const float* bihr = (const float*)d_in[8];
  const float* bhhr = (const float*)d_in[9];
  float* out = (float*)d_out;

  // workspace layout (u16 units)
  u16* ws = (u16*)d_ws;
  const size_t nE = (size_t)VOCAB * GCOLS;
  const size_t nEmb = (size_t)VOCAB * 1024;
  const size_t nW = (size_t)GCOLS * 1024;
  size_t off = 0;
  u16* Ef     = ws + off; off += nE;
  u16* Er     = ws + off; off += nE;
  u16* emb_b  = ws + off; off += nEmb;
  u16* Wihf_b = ws + off; off += nW;
  u16* Wihr_b = ws + off; off += nW;
  u16* Whhf_b = ws + off; off += nW;
  u16* Whhr_b = ws + off; off += nW;
  u16* hbuf   = ws + off; off += (size_t)2 * 2 * 128 * 1024;   // NEVER memset
  int* ctrl   = (int*)(ws + off);                              // bars[256]+tickets[8]

  // control block only: bars + tickets live at IF (agent atomics), DMA-coherent
  hipMemsetAsync(ctrl, 0, 2048, stream);

  // Phase 0: f32 -> bf16 copies
  k_cvt<<<dim3((nEmb / 4 + 255) / 256), dim3(256), 0, stream>>>(emb,  emb_b,  (int)nEmb);
  k_cvt<<<dim3((nW   / 4 + 255) / 256), dim3(256), 0, stream>>>(Wihf, Wihf_b, (int)nW);
  k_cvt<<<dim3((nW   / 4 + 255) / 256), dim3(256), 0, stream>>>(Wihr, Wihr_b, (int)nW);
  k_cvt<<<dim3((nW   / 4 + 255) / 256), dim3(256), 0, stream>>>(Whhf, Whhf_b, (int)nW);
  k_cvt<<<dim3((nW   / 4 + 255) / 256), dim3(256), 0, stream>>>(Whhr, Whhr_b, (int)nW);

  // Phase 1: vocab-level input projection tables
  k_gx<<<dim3(48 * 250), dim3(256), 0, stream>>>(emb_b, Wihf_b, bihf, Wihr_b, bihr, Ef, Er);

  // Phase 2: persistent recurrence, XCD-local groups (1 WG/CU forced by LDS)
  const int smem = 2 * 32 * GXS * 2      // gx double buffer      (13312 B)
                 + 4 * 4 * 64 * 5 * 16   // reduction buffer      (81920 B)
                 + 32 * 32 * 2           // output gather tile    ( 2048 B)
                 + 64;                   // broadcast cell
  hipFuncSetAttribute(reinterpret_cast<const void*>(k_rnn),
                      hipFuncAttributeMaxDynamicSharedMemorySize, smem);
  k_rnn<<<dim3(256), dim3(256), smem, stream>>>(seq, Ef, Er, Whhf_b, bhhf, Whhr_b, bhhr,
                                                hbuf, ctrl, out);
}